// Round 3
// baseline (349.828 us; speedup 1.0000x reference)
//
#include <hip/hip_runtime.h>

#define TT 16384
#define DD 4096
#define OO 4096
#define NE 8
#define RRK 64
#define KSPLIT 8
#define KCHUNK 512

typedef _Float16 f16x8 __attribute__((ext_vector_type(8)));
typedef _Float16 f16x4 __attribute__((ext_vector_type(4)));
typedef float f32x4 __attribute__((ext_vector_type(4)));

// workspace layout (bytes)
#define CNT_OFF 0             // 8 ints
#define PERM_OFF 1024         // 8*TT ints = 512KB
#define AT_OFF (1u << 20)     // 8*64*4096 f16 = 4MB: A^T [e][r][k]
#define BT_OFF (5u << 20)     // 8*4096*64 f16 = 4MB: B^T [e][o][r]
#define HP_OFF (9u << 20)     // 8*TT*64 f32 = 32MB: H k-partials, unscaled
#define H_OFF (41u << 20)     // TT*64 f16 = 2MB: reduced+scaled H

// ---------------------------------------------------------------------------
// prep: scatter tokens into per-adapter buckets; transpose+cast A and B to f16
// ---------------------------------------------------------------------------
__global__ void prep_kernel(const int* __restrict__ ids,
                            const float* __restrict__ A,
                            const float* __restrict__ B,
                            int* __restrict__ cnt,
                            int* __restrict__ perm,
                            _Float16* __restrict__ At,
                            _Float16* __restrict__ Bt) {
  const int bid = blockIdx.x, tid = threadIdx.x;
  if (bid < 64) {                      // scatter
    int t = bid * 256 + tid;
    int e = ids[t];
    int pos = atomicAdd(&cnt[e], 1);
    perm[e * TT + pos] = t;
    return;
  }
  __shared__ float tile[64][65];
  if (bid < 576) {                     // A[e][k][r] -> At[e][r][k]
    int idx = bid - 64;
    int e = idx >> 6, kb = (idx & 63) << 6;
    #pragma unroll
    for (int i = 0; i < 16; ++i) {
      int lin = i * 256 + tid;
      int kr = lin >> 6, r = lin & 63;
      tile[kr][r] = A[((size_t)e * DD + kb + kr) * RRK + r];
    }
    __syncthreads();
    #pragma unroll
    for (int i = 0; i < 16; ++i) {
      int lin = i * 256 + tid;
      int r = lin >> 6, kk = lin & 63;
      At[((size_t)e * RRK + r) * DD + kb + kk] = (_Float16)tile[kk][r];
    }
  } else {                             // B[e][r][o] -> Bt[e][o][r]
    int idx = bid - 576;
    int e = idx >> 6, ob = (idx & 63) << 6;
    #pragma unroll
    for (int i = 0; i < 16; ++i) {
      int lin = i * 256 + tid;
      int r = lin >> 6, o = lin & 63;
      tile[r][o] = B[((size_t)e * RRK + r) * OO + ob + o];
    }
    __syncthreads();
    #pragma unroll
    for (int i = 0; i < 16; ++i) {
      int lin = i * 256 + tid;
      int o = lin >> 6, r2 = lin & 63;
      Bt[((size_t)e * OO + ob + o) * RRK + r2] = (_Float16)tile[r2][o];
    }
  }
}

// ---------------------------------------------------------------------------
// stage 1: HP[s][t][:] = x[t][ks..] @ A[e][ks..]   (k-split by 8, f32, unscaled)
// LDS-free, barrier-free: operands loaded straight into MFMA fragments.
// At (4MB) is L2-resident; x streams from HBM exactly once.
// ---------------------------------------------------------------------------
__global__ __launch_bounds__(256, 4)
void lora_stage1(const float* __restrict__ x,
                 const _Float16* __restrict__ At,
                 const int* __restrict__ cnt,
                 const int* __restrict__ perm,
                 float* __restrict__ HP) {
  const int tid = threadIdx.x;
  const int lane = tid & 63, w = tid >> 6;
  const int lr = lane & 15;
  const int kq = (lane >> 4) << 3;

  int tiles = 0;
  #pragma unroll
  for (int ee = 0; ee < NE; ++ee) tiles += (cnt[ee] + 63) >> 6;

  for (int wi = blockIdx.x; wi < tiles * KSPLIT; wi += gridDim.x) {
    int tile = wi >> 3, s = wi & 7;
    int e = 0, base = 0, n_e = 0;
    {
      int acc0 = 0;
      #pragma unroll
      for (int ee = 0; ee < NE; ++ee) {
        int c = cnt[ee];
        int tl = (c + 63) >> 6;
        if (tile >= acc0 && tile < acc0 + tl) { e = ee; base = acc0; n_e = c; }
        acc0 += tl;
      }
    }
    int m0 = (tile - base) << 6;
    int kbase = s * KCHUNK;

    // A-operand row: token for this lane (row = lane&15 within 16-row frag)
    int arow = m0 + w * 16 + lr;
    int atok = perm[e * TT + (arow < n_e ? arow : n_e - 1)];
    const float* xp = x + (size_t)atok * DD + kbase + kq;
    const _Float16* ap = At + (size_t)e * RRK * DD + kbase + kq;

    f32x4 acc[4] = {};

    for (int k0 = 0; k0 < KCHUNK; k0 += 64) {
      f16x8 xa[2];
      #pragma unroll
      for (int ks = 0; ks < 2; ++ks) {
        float4 u0 = *(const float4*)(xp + k0 + ks * 32);
        float4 u1 = *(const float4*)(xp + k0 + ks * 32 + 4);
        f16x8 v;
        v[0] = (_Float16)u0.x; v[1] = (_Float16)u0.y;
        v[2] = (_Float16)u0.z; v[3] = (_Float16)u0.w;
        v[4] = (_Float16)u1.x; v[5] = (_Float16)u1.y;
        v[6] = (_Float16)u1.z; v[7] = (_Float16)u1.w;
        xa[ks] = v;
      }
      #pragma unroll
      for (int ks = 0; ks < 2; ++ks) {
        #pragma unroll
        for (int nf = 0; nf < 4; ++nf) {
          f16x8 bfr = *(const f16x8*)(ap + (size_t)(nf * 16 + lr) * DD + k0 + ks * 32);
          acc[nf] = __builtin_amdgcn_mfma_f32_16x16x32_f16(xa[ks], bfr, acc[nf], 0, 0, 0);
        }
      }
    }

    // epilogue: D rows = tokens ((lane>>4)*4+reg), cols = r (nf*16 + lane&15)
    const int rq = (lane >> 4) << 2;
    #pragma unroll
    for (int rg = 0; rg < 4; ++rg) {
      int row = m0 + w * 16 + rq + rg;
      if (row < n_e) {
        int tk = perm[e * TT + row];
        float* hp = HP + ((size_t)s * TT + tk) * RRK + lr;
        #pragma unroll
        for (int nf = 0; nf < 4; ++nf) hp[nf * 16] = acc[nf][rg];
      }
    }
  }
}

// ---------------------------------------------------------------------------
// reduce: H[t][r] = scaling[ids[t]] * sum_s HP[s][t][r]   (f32 -> f16)
// ---------------------------------------------------------------------------
__global__ void lora_reduce(const float* __restrict__ HP,
                            const float* __restrict__ scaling,
                            const int* __restrict__ ids,
                            _Float16* __restrict__ H) {
  int i = blockIdx.x * 256 + threadIdx.x;    // one thread per 4 r-values
  int t = i >> 4;
  int rg = (i & 15) << 2;
  float s = scaling[ids[t]];
  f32x4 sum = {};
  #pragma unroll
  for (int sp = 0; sp < KSPLIT; ++sp) {
    sum += *(const f32x4*)(HP + ((size_t)sp * TT + t) * RRK + rg);
  }
  f16x4 h;
  #pragma unroll
  for (int j = 0; j < 4; ++j) h[j] = (_Float16)(sum[j] * s);
  *(f16x4*)(H + (size_t)t * RRK + rg) = h;
}

// ---------------------------------------------------------------------------
// stage 2: out[t][:] = base[t][:] + H[t] @ B[e]
// LDS-free, barrier-free. D = B^T(A-op) x H^T(B-op): lane owns one token row,
// 4 consecutive cols per of -> float4 epilogue. Bt/H are L2-resident.
// ---------------------------------------------------------------------------
__global__ __launch_bounds__(256, 4)
void lora_stage2(const float* __restrict__ baseo,
                 const _Float16* __restrict__ Bt,
                 const _Float16* __restrict__ H,
                 const int* __restrict__ cnt,
                 const int* __restrict__ perm,
                 float* __restrict__ out) {
  const int tid = threadIdx.x;
  const int lane = tid & 63, w = tid >> 6;
  const int lr = lane & 15;
  const int kq = (lane >> 4) << 3;
  const int g4 = (lane >> 4) << 2;

  int tot = 0;
  #pragma unroll
  for (int ee = 0; ee < NE; ++ee) tot += ((cnt[ee] + 63) >> 6) << 4;

  for (int wi = blockIdx.x; wi < tot; wi += gridDim.x) {
    int e = 0, base = 0, n_e = 0;
    {
      int acc0 = 0;
      #pragma unroll
      for (int ee = 0; ee < NE; ++ee) {
        int c = cnt[ee];
        int tl = ((c + 63) >> 6) << 4;
        if (wi >= acc0 && wi < acc0 + tl) { e = ee; base = acc0; n_e = c; }
        acc0 += tl;
      }
    }
    int local = wi - base;
    int tiles_m = (n_e + 63) >> 6;
    int mt = local % tiles_m;           // consecutive blocks share the Bt panel
    int nt = local / tiles_m;
    int m0 = mt << 6, o0 = nt << 8;

    int row = m0 + w * 16 + lr;
    bool valid = row < n_e;
    int tk = perm[e * TT + (valid ? row : n_e - 1)];

    // H fragments (B-operand: cols = tokens)
    const _Float16* hp = H + (size_t)tk * RRK + kq;
    f16x8 hf0 = *(const f16x8*)(hp);
    f16x8 hf1 = *(const f16x8*)(hp + 32);

    const _Float16* bp = Bt + ((size_t)e * OO + o0 + lr) * RRK + kq;

    f32x4 acc[16];
    #pragma unroll
    for (int of = 0; of < 16; ++of) acc[of] = (f32x4){0.f, 0.f, 0.f, 0.f};

    #pragma unroll
    for (int of = 0; of < 16; ++of) {
      f16x8 b0 = *(const f16x8*)(bp + (size_t)of * 16 * RRK);
      f16x8 b1 = *(const f16x8*)(bp + (size_t)of * 16 * RRK + 32);
      acc[of] = __builtin_amdgcn_mfma_f32_16x16x32_f16(b0, hf0, acc[of], 0, 0, 0);
      acc[of] = __builtin_amdgcn_mfma_f32_16x16x32_f16(b1, hf1, acc[of], 0, 0, 0);
    }

    if (valid) {
      size_t rowoff = (size_t)tk * OO + o0 + g4;
      #pragma unroll
      for (int of = 0; of < 16; ++of) {
        size_t off = rowoff + of * 16;
        float4 b4 = *(const float4*)(baseo + off);
        float4 r4;
        r4.x = b4.x + acc[of][0];
        r4.y = b4.y + acc[of][1];
        r4.z = b4.z + acc[of][2];
        r4.w = b4.w + acc[of][3];
        *(float4*)(out + off) = r4;
      }
    }
  }
}

extern "C" void kernel_launch(void* const* d_in, const int* in_sizes, int n_in,
                              void* d_out, int out_size, void* d_ws, size_t ws_size,
                              hipStream_t stream) {
  const float* x = (const float*)d_in[0];
  const float* baseo = (const float*)d_in[1];
  const float* A = (const float*)d_in[2];
  const float* B = (const float*)d_in[3];
  const float* scaling = (const float*)d_in[4];
  const int* ids = (const int*)d_in[5];
  float* out = (float*)d_out;
  char* ws = (char*)d_ws;

  int* cnt = (int*)(ws + CNT_OFF);
  int* perm = (int*)(ws + PERM_OFF);
  _Float16* At = (_Float16*)(ws + AT_OFF);
  _Float16* Bt = (_Float16*)(ws + BT_OFF);
  float* HP = (float*)(ws + HP_OFF);
  _Float16* H = (_Float16*)(ws + H_OFF);

  hipMemsetAsync(cnt, 0, NE * sizeof(int), stream);
  hipLaunchKernelGGL(prep_kernel, dim3(1088), dim3(256), 0, stream,
                     ids, A, B, cnt, perm, At, Bt);
  hipLaunchKernelGGL(lora_stage1, dim3(2048), dim3(256), 0, stream,
                     x, At, cnt, perm, HP);
  hipLaunchKernelGGL(lora_reduce, dim3(1024), dim3(256), 0, stream,
                     HP, scaling, ids, H);
  hipLaunchKernelGGL(lora_stage2, dim3(4096), dim3(256), 0, stream,
                     baseo, Bt, H, cnt, perm, out);
}